// Round 3
// baseline (553.069 us; speedup 1.0000x reference)
//
#include <hip/hip_runtime.h>
#include <float.h>

#define N_PTS 262144
#define K_CL  1024
#define D     64
#define BN    128   // points per block
#define BK    128   // centroids per tile
#define NTILE (K_CL / BK)
#define MARGIN_S 0.5f   // score margin = 0.5 -> distance margin 1.0 (fp16 err <= ~0.08)

typedef _Float16 f16;
typedef _Float16 half8 __attribute__((ext_vector_type(8)));
typedef float    f32x4 __attribute__((ext_vector_type(4)));

// ---- prep: csq (fp32, round-1 arithmetic), csqh = 0.5*csq, cent16 = fp16 pre-swizzled
// swizzle: phys 16B-chunk pc of row k holds logical chunk pc ^ (k&7)
__global__ __launch_bounds__(256) void prep_kernel(const float* __restrict__ cent,
                                                   float* __restrict__ csq,
                                                   float* __restrict__ csqh,
                                                   f16* __restrict__ cent16) {
    int k = blockIdx.x * 256 + threadIdx.x;
    if (k >= K_CL) return;
    const float* row = &cent[(size_t)k * D];
    float s = 0.f;
    #pragma unroll
    for (int d = 0; d < D; ++d) s = fmaf(row[d], row[d], s);
    csq[k]  = s;
    csqh[k] = 0.5f * s;
    int sw = k & 7;
    #pragma unroll
    for (int lch = 0; lch < 8; ++lch) {
        half8 h;
        #pragma unroll
        for (int e = 0; e < 8; ++e) h[e] = (f16)row[lch * 8 + e];
        *reinterpret_cast<half8*>(&cent16[(size_t)k * D + (size_t)((lch ^ sw) * 8)]) = h;
    }
}

// exact fp32 distance, replicating round-1's accepted arithmetic exactly
__device__ __forceinline__ float exact_dist(const float* __restrict__ xr,
                                            const float* __restrict__ cr,
                                            float xsq, float cs) {
    float dot = 0.f;
    #pragma unroll
    for (int d = 0; d < D; ++d) dot = fmaf(xr[d], cr[d], dot);
    return (xsq - 2.0f * dot) + cs;
}

__device__ __forceinline__ half8 frag_rd(const f16* base, int row, int ch) {
    // logical chunk ch of row -> phys chunk ch ^ (row&7)  (8 halves = 16 B)
    return *reinterpret_cast<const half8*>(&base[row * D + ((ch ^ (row & 7)) * 8)]);
}

__global__ __launch_bounds__(256, 3) void assign_kernel(
    const float* __restrict__ batch,
    const f16*   __restrict__ cent16,
    const float* __restrict__ csq,
    const float* __restrict__ csqh,
    const float* __restrict__ cent,
    float* __restrict__ out_assign)
{
    __shared__ f16 P16[BN * D];                    // 16 KB points (swizzled phys)
    __shared__ f16 C16[BK * D];                    // 16 KB centroid tile
    __shared__ __align__(16) float csqh_s[BK];     // 512 B

    const int tid  = threadIdx.x;
    const int wave = tid >> 6;
    const int lane = tid & 63;
    const int lo   = lane & 15;
    const int hi   = lane >> 4;
    const int gp0  = blockIdx.x * BN;

    // ---- stage P16 once: fp32 global -> fp16 swizzled LDS (coalesced 32B/lane)
    #pragma unroll
    for (int it = 0; it < 4; ++it) {
        int u = tid + 256 * it;            // (p, lch)
        int p = u >> 3, lch = u & 7;
        const float* src = &batch[(size_t)(gp0 + p) * D + lch * 8];
        half8 h;
        #pragma unroll
        for (int e = 0; e < 8; ++e) h[e] = (f16)src[e];
        *reinterpret_cast<half8*>(&P16[p * D + ((lch ^ (p & 7)) * 8)]) = h;
    }

    const int prow0 = wave * 32 + lo;          // point row, n=0
    const int prow1 = wave * 32 + 16 + lo;     // point row, n=1

    float m0 = -FLT_MAX, m1 = -FLT_MAX;

    // =================== PASS 1: per-lane approx max score ===================
    for (int tile = 0; tile < NTILE; ++tile) {
        __syncthreads();
        #pragma unroll
        for (int it = 0; it < 4; ++it) {
            int u = tid + 256 * it;
            *reinterpret_cast<half8*>(&C16[u * 8]) =
                *reinterpret_cast<const half8*>(&cent16[(size_t)tile * BK * D + (size_t)u * 8]);
        }
        if (tid < BK) csqh_s[tid] = csqh[tile * BK + tid];
        __syncthreads();

        f32x4 acc[8][2];
        #pragma unroll
        for (int m = 0; m < 8; ++m) {
            acc[m][0] = f32x4{0.f, 0.f, 0.f, 0.f};
            acc[m][1] = f32x4{0.f, 0.f, 0.f, 0.f};
        }
        #pragma unroll
        for (int ks = 0; ks < 2; ++ks) {
            half8 pf0 = frag_rd(P16, prow0, ks * 4 + hi);
            half8 pf1 = frag_rd(P16, prow1, ks * 4 + hi);
            #pragma unroll
            for (int m = 0; m < 8; ++m) {
                half8 cf = frag_rd(C16, m * 16 + lo, ks * 4 + hi);
                acc[m][0] = __builtin_amdgcn_mfma_f32_16x16x32_f16(cf, pf0, acc[m][0], 0, 0, 0);
                acc[m][1] = __builtin_amdgcn_mfma_f32_16x16x32_f16(cf, pf1, acc[m][1], 0, 0, 0);
            }
        }
        #pragma unroll
        for (int m = 0; m < 8; ++m) {
            f32x4 ch4 = *reinterpret_cast<const f32x4*>(&csqh_s[m * 16 + hi * 4]);
            f32x4 s0 = acc[m][0] - ch4;
            f32x4 s1 = acc[m][1] - ch4;
            m0 = fmaxf(m0, fmaxf(fmaxf(s0.x, s0.y), fmaxf(s0.z, s0.w)));
            m1 = fmaxf(m1, fmaxf(fmaxf(s1.x, s1.y), fmaxf(s1.z, s1.w)));
        }
    }

    // cross-lane max over the 4 hi-groups holding the same point
    m0 = fmaxf(m0, __shfl_xor(m0, 16)); m0 = fmaxf(m0, __shfl_xor(m0, 32));
    m1 = fmaxf(m1, __shfl_xor(m1, 16)); m1 = fmaxf(m1, __shfl_xor(m1, 32));
    const float thr0 = m0 - MARGIN_S, thr1 = m1 - MARGIN_S;

    int cnt0 = 0, cnt1 = 0;
    int la0 = 0, la1 = 0, la2 = 0, la3 = 0;
    int lb0 = 0, lb1 = 0, lb2 = 0, lb3 = 0;

    // =================== PASS 2: collect candidates within margin ===================
    for (int tile = 0; tile < NTILE; ++tile) {
        __syncthreads();
        #pragma unroll
        for (int it = 0; it < 4; ++it) {
            int u = tid + 256 * it;
            *reinterpret_cast<half8*>(&C16[u * 8]) =
                *reinterpret_cast<const half8*>(&cent16[(size_t)tile * BK * D + (size_t)u * 8]);
        }
        if (tid < BK) csqh_s[tid] = csqh[tile * BK + tid];
        __syncthreads();

        f32x4 acc[8][2];
        #pragma unroll
        for (int m = 0; m < 8; ++m) {
            acc[m][0] = f32x4{0.f, 0.f, 0.f, 0.f};
            acc[m][1] = f32x4{0.f, 0.f, 0.f, 0.f};
        }
        #pragma unroll
        for (int ks = 0; ks < 2; ++ks) {
            half8 pf0 = frag_rd(P16, prow0, ks * 4 + hi);
            half8 pf1 = frag_rd(P16, prow1, ks * 4 + hi);
            #pragma unroll
            for (int m = 0; m < 8; ++m) {
                half8 cf = frag_rd(C16, m * 16 + lo, ks * 4 + hi);
                acc[m][0] = __builtin_amdgcn_mfma_f32_16x16x32_f16(cf, pf0, acc[m][0], 0, 0, 0);
                acc[m][1] = __builtin_amdgcn_mfma_f32_16x16x32_f16(cf, pf1, acc[m][1], 0, 0, 0);
            }
        }
        #pragma unroll
        for (int m = 0; m < 8; ++m) {
            f32x4 ch4 = *reinterpret_cast<const f32x4*>(&csqh_s[m * 16 + hi * 4]);
            f32x4 s0 = acc[m][0] - ch4;
            f32x4 s1 = acc[m][1] - ch4;
            int cbase = tile * BK + m * 16 + hi * 4;
            float mx0 = fmaxf(fmaxf(s0.x, s0.y), fmaxf(s0.z, s0.w));
            if (mx0 >= thr0) {
                #pragma unroll
                for (int r = 0; r < 4; ++r) {
                    float sv = (r == 0) ? s0.x : (r == 1) ? s0.y : (r == 2) ? s0.z : s0.w;
                    if (sv >= thr0) {
                        if      (cnt0 == 0) la0 = cbase + r;
                        else if (cnt0 == 1) la1 = cbase + r;
                        else if (cnt0 == 2) la2 = cbase + r;
                        else if (cnt0 == 3) la3 = cbase + r;
                        cnt0++;
                    }
                }
            }
            float mx1 = fmaxf(fmaxf(s1.x, s1.y), fmaxf(s1.z, s1.w));
            if (mx1 >= thr1) {
                #pragma unroll
                for (int r = 0; r < 4; ++r) {
                    float sv = (r == 0) ? s1.x : (r == 1) ? s1.y : (r == 2) ? s1.z : s1.w;
                    if (sv >= thr1) {
                        if      (cnt1 == 0) lb0 = cbase + r;
                        else if (cnt1 == 1) lb1 = cbase + r;
                        else if (cnt1 == 2) lb2 = cbase + r;
                        else if (cnt1 == 3) lb3 = cbase + r;
                        cnt1++;
                    }
                }
            }
        }
    }

    // =================== exact fp32 resolve (round-1 arithmetic) ===================
    float bd0 = FLT_MAX, bd1 = FLT_MAX;
    int   bi0 = 0x7fffffff, bi1 = 0x7fffffff;

    if (cnt0 > 0) {
        const float* xr = &batch[(size_t)(gp0 + prow0) * D];
        float xsq = 0.f;
        #pragma unroll
        for (int d = 0; d < D; ++d) xsq = fmaf(xr[d], xr[d], xsq);
        if (cnt0 <= 4) {
            #pragma unroll
            for (int r = 0; r < 4; ++r) {
                int c = (r == 0) ? la0 : (r == 1) ? la1 : (r == 2) ? la2 : la3;
                if (r < cnt0) {
                    float dd = exact_dist(xr, &cent[(size_t)c * D], xsq, csq[c]);
                    if (dd < bd0 || (dd == bd0 && c < bi0)) { bd0 = dd; bi0 = c; }
                }
            }
        } else {  // overflow: exact scan of this lane's row slice
            for (int t16 = 0; t16 < 64; ++t16) {
                #pragma unroll
                for (int r = 0; r < 4; ++r) {
                    int c = t16 * 16 + hi * 4 + r;
                    float dd = exact_dist(xr, &cent[(size_t)c * D], xsq, csq[c]);
                    if (dd < bd0 || (dd == bd0 && c < bi0)) { bd0 = dd; bi0 = c; }
                }
            }
        }
    }
    if (cnt1 > 0) {
        const float* xr = &batch[(size_t)(gp0 + prow1) * D];
        float xsq = 0.f;
        #pragma unroll
        for (int d = 0; d < D; ++d) xsq = fmaf(xr[d], xr[d], xsq);
        if (cnt1 <= 4) {
            #pragma unroll
            for (int r = 0; r < 4; ++r) {
                int c = (r == 0) ? lb0 : (r == 1) ? lb1 : (r == 2) ? lb2 : lb3;
                if (r < cnt1) {
                    float dd = exact_dist(xr, &cent[(size_t)c * D], xsq, csq[c]);
                    if (dd < bd1 || (dd == bd1 && c < bi1)) { bd1 = dd; bi1 = c; }
                }
            }
        } else {
            for (int t16 = 0; t16 < 64; ++t16) {
                #pragma unroll
                for (int r = 0; r < 4; ++r) {
                    int c = t16 * 16 + hi * 4 + r;
                    float dd = exact_dist(xr, &cent[(size_t)c * D], xsq, csq[c]);
                    if (dd < bd1 || (dd == bd1 && c < bi1)) { bd1 = dd; bi1 = c; }
                }
            }
        }
    }

    // cross-lane (hi-group) min reduce with first-index tie-break
    #pragma unroll
    for (int off = 16; off <= 32; off <<= 1) {
        float od = __shfl_xor(bd0, off); int oi = __shfl_xor(bi0, off);
        if (od < bd0 || (od == bd0 && oi < bi0)) { bd0 = od; bi0 = oi; }
        float oe = __shfl_xor(bd1, off); int oj = __shfl_xor(bi1, off);
        if (oe < bd1 || (oe == bd1 && oj < bi1)) { bd1 = oe; bi1 = oj; }
    }

    if (hi == 0) {
        out_assign[gp0 + prow0] = (float)bi0;
        out_assign[gp0 + prow1] = (float)bi1;
    }
}

// ---- gather-scan scatter: 2048 waves, each owns (cluster quad, eighth of points).
// No atomics; deterministic; rows read coalesced (lane = dim).
#define EIGHTHS 8
#define PTS_PER_EIGHTH (N_PTS / EIGHTHS)   // 32768

__global__ __launch_bounds__(256) void scatter_scan_kernel(
    const float* __restrict__ batch,
    const float* __restrict__ assignF,
    float* __restrict__ partial,        // [8][K_CL][D]
    float* __restrict__ cnt_partial)    // [8][K_CL]
{
    const int wave = threadIdx.x >> 6;
    const int lane = threadIdx.x & 63;
    const int gw   = blockIdx.x * 4 + wave;     // 0..2047
    const int cq   = gw >> 3;                   // cluster quad 0..255
    const int eighth = gw & 7;
    const int c0   = cq * 4;
    const size_t pstart = (size_t)eighth * PTS_PER_EIGHTH;

    float acc0 = 0.f, acc1 = 0.f, acc2 = 0.f, acc3 = 0.f;
    int   n0 = 0, n1 = 0, n2 = 0, n3 = 0;

    for (int chunk = 0; chunk < PTS_PER_EIGHTH; chunk += 256) {
        const size_t pb = pstart + chunk;
        float4 av = *reinterpret_cast<const float4*>(&assignF[pb + (size_t)lane * 4]);
        #pragma unroll
        for (int j = 0; j < 4; ++j) {
            int a = (int)((j == 0) ? av.x : (j == 1) ? av.y : (j == 2) ? av.z : av.w);
            bool match = (a >= c0) && (a < c0 + 4);
            unsigned long long mask = __ballot(match);
            while (mask) {
                int bit = __builtin_ctzll(mask);
                mask &= mask - 1;
                int p = (int)pb + bit * 4 + j;
                int c = __builtin_amdgcn_readlane(a, bit) - c0;
                float v = batch[(size_t)p * D + lane];
                if      (c == 0) { acc0 += v; n0++; }
                else if (c == 1) { acc1 += v; n1++; }
                else if (c == 2) { acc2 += v; n2++; }
                else             { acc3 += v; n3++; }
            }
        }
    }

    float* pr = &partial[((size_t)eighth * K_CL + c0) * D];
    pr[0 * D + lane] = acc0;
    pr[1 * D + lane] = acc1;
    pr[2 * D + lane] = acc2;
    pr[3 * D + lane] = acc3;
    if (lane == 0) {
        float* cp = &cnt_partial[eighth * K_CL + c0];
        cp[0] = (float)n0; cp[1] = (float)n1; cp[2] = (float)n2; cp[3] = (float)n3;
    }
}

__global__ __launch_bounds__(256) void reduce_kernel(
    const float* __restrict__ partial,
    const float* __restrict__ cnt_partial,
    float* __restrict__ out_counts,
    float* __restrict__ out_sums)
{
    int idx = blockIdx.x * 256 + threadIdx.x;
    if (idx < K_CL * D) {
        float s = 0.f;
        #pragma unroll
        for (int e = 0; e < EIGHTHS; ++e) s += partial[(size_t)e * K_CL * D + idx];
        out_sums[idx] = s;
    } else if (idx < K_CL * D + K_CL) {
        int c = idx - K_CL * D;
        float s = 0.f;
        #pragma unroll
        for (int e = 0; e < EIGHTHS; ++e) s += cnt_partial[e * K_CL + c];
        out_counts[c] = s;
    }
}

// ---- fallback scatter (atomics) if ws is too small for partials
__global__ __launch_bounds__(256) void scatter_atomic_kernel(
    const float* __restrict__ batch,
    const float* __restrict__ assignF,
    float* __restrict__ out_counts,
    float* __restrict__ out_sums)
{
    const int gwave = (blockIdx.x * 256 + threadIdx.x) >> 6;  // 16384 waves
    const int lane  = threadIdx.x & 63;
    #pragma unroll 4
    for (int it = 0; it < 16; ++it) {
        int p = gwave * 16 + it;
        int a = (int)assignF[p];
        if (lane == 0) atomicAdd(&out_counts[a], 1.0f);
        atomicAdd(&out_sums[(size_t)a * D + lane], batch[(size_t)p * D + lane]);
    }
}

extern "C" void kernel_launch(void* const* d_in, const int* in_sizes, int n_in,
                              void* d_out, int out_size, void* d_ws, size_t ws_size,
                              hipStream_t stream) {
    const float* batch = (const float*)d_in[0];
    const float* cent  = (const float*)d_in[1];
    float* out        = (float*)d_out;
    float* out_assign = out;
    float* out_counts = out + N_PTS;
    float* out_sums   = out + N_PTS + K_CL;

    float* csq    = (float*)d_ws;                                 // 4 KB
    float* csqh   = csq + K_CL;                                   // 4 KB
    f16*   cent16 = (f16*)((char*)d_ws + 8192);                   // 128 KB
    float* partial     = (float*)((char*)d_ws + 8192 + 131072);   // 2 MB
    float* cnt_partial = partial + (size_t)EIGHTHS * K_CL * D;    // 32 KB

    const size_t need = 8192 + 131072 + (size_t)EIGHTHS * K_CL * D * 4 + (size_t)EIGHTHS * K_CL * 4;

    prep_kernel<<<K_CL / 256, 256, 0, stream>>>(cent, csq, csqh, cent16);
    assign_kernel<<<N_PTS / BN, 256, 0, stream>>>(batch, cent16, csq, csqh, cent, out_assign);

    if (ws_size >= need) {
        scatter_scan_kernel<<<512, 256, 0, stream>>>(batch, out_assign, partial, cnt_partial);
        reduce_kernel<<<(K_CL * D + K_CL + 255) / 256, 256, 0, stream>>>(
            partial, cnt_partial, out_counts, out_sums);
    } else {
        hipMemsetAsync(out_counts, 0, (size_t)(K_CL + K_CL * D) * sizeof(float), stream);
        scatter_atomic_kernel<<<N_PTS / (16 * 4), 256, 0, stream>>>(
            batch, out_assign, out_counts, out_sums);
    }
}